// Round 1
// baseline (2508.999 us; speedup 1.0000x reference)
//
#include <hip/hip_runtime.h>
#include <hip/hip_bf16.h>
#include <math.h>

// Problem constants
#define NB    8          // batch
#define CIN   512        // in channels
#define HW    3136       // 56*56
#define CH    128        // attention channels
#define TCH   384        // 3*CH
#define SCALE 0.08838834764831845f   // 128^-0.5
#define BNEPS 1e-5f

// ---------------------------------------------------------------------------
// Kernel 1: proj = W_w @ x[n] + b  ->  tpg[n][384][3136]
// Tiled f32 GEMM, 64x64 tile, 256 threads, 4x4 microtile, K-tile 16.
// ---------------------------------------------------------------------------
__global__ __launch_bounds__(256) void proj_kernel(const float* __restrict__ x,
                                                   const float* __restrict__ Ww,
                                                   const float* __restrict__ Wb,
                                                   float* __restrict__ tpg) {
    const int n  = blockIdx.z;
    const int m0 = blockIdx.y * 64;   // over 384
    const int q0 = blockIdx.x * 64;   // over 3136
    const int tid = threadIdx.x;
    const int tx = tid & 15, ty = tid >> 4;

    __shared__ float As[16][65];   // [k][m]
    __shared__ float Bs[16][65];   // [k][q]

    float acc[4][4] = {};
    const float* xn = x + (size_t)n * CIN * HW;

    for (int k0 = 0; k0 < CIN; k0 += 16) {
#pragma unroll
        for (int l = 0; l < 4; ++l) {          // A tile: 64m x 16k
            int elem = l * 256 + tid;
            int m = elem >> 4, k = elem & 15;
            As[k][m] = Ww[(size_t)(m0 + m) * CIN + k0 + k];
        }
#pragma unroll
        for (int l = 0; l < 4; ++l) {          // B tile: 16k x 64q
            int elem = l * 256 + tid;
            int k = elem >> 6, q = elem & 63;
            Bs[k][q] = xn[(size_t)(k0 + k) * HW + q0 + q];
        }
        __syncthreads();
#pragma unroll
        for (int k = 0; k < 16; ++k) {
            float a[4], b[4];
#pragma unroll
            for (int i = 0; i < 4; ++i) a[i] = As[k][i * 16 + ty];
#pragma unroll
            for (int j = 0; j < 4; ++j) b[j] = Bs[k][j * 16 + tx];
#pragma unroll
            for (int i = 0; i < 4; ++i)
#pragma unroll
                for (int j = 0; j < 4; ++j) acc[i][j] += a[i] * b[j];
        }
        __syncthreads();
    }

    float* outn = tpg + (size_t)n * TCH * HW;
#pragma unroll
    for (int i = 0; i < 4; ++i) {
        int m = m0 + i * 16 + ty;
        float bias = Wb[m];
#pragma unroll
        for (int j = 0; j < 4; ++j) {
            outn[(size_t)m * HW + q0 + j * 16 + tx] = acc[i][j] + bias;
        }
    }
}

// ---------------------------------------------------------------------------
// Kernel 2: flash attention over HW tokens, head dim 128.
//   Q[q][c] = t[c][q], K[k][c] = p[c][k], V[v][c] = g[c][v]
//   att[c][q] = sum_v softmax_q(Q K^T * SCALE)[v] * V[v][c]
// One block per (q-tile of 32, batch). 256 threads as 16x16; each thread owns
// 2 q-rows x (2 k-cols in S) and 2 q-rows x 8 c-slices of O.
// ---------------------------------------------------------------------------
__global__ __launch_bounds__(256) void attn_kernel(const float* __restrict__ tpg,
                                                   float* __restrict__ att) {
    const int n  = blockIdx.y;
    const int q0 = blockIdx.x * 32;
    const int tid = threadIdx.x;
    const int tx = tid & 15, ty = tid >> 4;

    const float* tn = tpg + (size_t)n * TCH * HW;       // t: [128][3136]
    const float* pn = tn + (size_t)CH * HW;             // p
    const float* gn = pn + (size_t)CH * HW;             // g

    __shared__ float Qs[CH][34];   // [c][q]  (pad 2 keeps float2 alignment)
    __shared__ float Ks[CH][34];   // [c][k]
    __shared__ float Vs[CH][34];   // [c][k]
    __shared__ float Ps[32][34];   // [q][k]

    // stage Q tile (c-major, same layout as global)
#pragma unroll
    for (int l = 0; l < 16; ++l) {
        int elem = l * 256 + tid;
        int c = elem >> 5, q = elem & 31;
        Qs[c][q] = tn[(size_t)c * HW + q0 + q];
    }

    float m_i[2] = {-1e30f, -1e30f};
    float l_i[2] = {0.f, 0.f};
    float O[2][8] = {};
    __syncthreads();

    for (int k0 = 0; k0 < HW; k0 += 32) {
        // stage K, V tiles
#pragma unroll
        for (int l = 0; l < 16; ++l) {
            int elem = l * 256 + tid;
            int c = elem >> 5, k = elem & 31;
            Ks[c][k] = pn[(size_t)c * HW + k0 + k];
            Vs[c][k] = gn[(size_t)c * HW + k0 + k];
        }
        __syncthreads();

        // S tile: 2x2 per thread, rows q = 2ty+{0,1}, cols k = 2tx+{0,1}
        float s00 = 0.f, s01 = 0.f, s10 = 0.f, s11 = 0.f;
#pragma unroll 4
        for (int c = 0; c < CH; ++c) {
            float2 qv = *(const float2*)&Qs[c][2 * ty];
            float2 kv = *(const float2*)&Ks[c][2 * tx];
            s00 += qv.x * kv.x; s01 += qv.x * kv.y;
            s10 += qv.y * kv.x; s11 += qv.y * kv.y;
        }
        s00 *= SCALE; s01 *= SCALE; s10 *= SCALE; s11 *= SCALE;

        // row max across the 16 tx lanes (lanes ty*16+tx, xor<=8 stays in row)
        float r0 = fmaxf(s00, s01), r1 = fmaxf(s10, s11);
#pragma unroll
        for (int off = 1; off < 16; off <<= 1) {
            r0 = fmaxf(r0, __shfl_xor(r0, off));
            r1 = fmaxf(r1, __shfl_xor(r1, off));
        }
        float nm0 = fmaxf(m_i[0], r0), nm1 = fmaxf(m_i[1], r1);
        float f0 = __expf(m_i[0] - nm0), f1 = __expf(m_i[1] - nm1);
        float p00 = __expf(s00 - nm0), p01 = __expf(s01 - nm0);
        float p10 = __expf(s10 - nm1), p11 = __expf(s11 - nm1);
        float rs0 = p00 + p01, rs1 = p10 + p11;
#pragma unroll
        for (int off = 1; off < 16; off <<= 1) {
            rs0 += __shfl_xor(rs0, off);
            rs1 += __shfl_xor(rs1, off);
        }
        l_i[0] = l_i[0] * f0 + rs0;  l_i[1] = l_i[1] * f1 + rs1;
        m_i[0] = nm0;                m_i[1] = nm1;
#pragma unroll
        for (int cc = 0; cc < 8; ++cc) { O[0][cc] *= f0; O[1][cc] *= f1; }

        Ps[2 * ty][2 * tx]     = p00;  Ps[2 * ty][2 * tx + 1]     = p01;
        Ps[2 * ty + 1][2 * tx] = p10;  Ps[2 * ty + 1][2 * tx + 1] = p11;
        __syncthreads();

        // O[q][c] += P[q][k] * V[k][c]; thread owns c = tx + cc*16
#pragma unroll
        for (int k = 0; k < 32; ++k) {
            float pv0 = Ps[2 * ty][k], pv1 = Ps[2 * ty + 1][k];
#pragma unroll
            for (int cc = 0; cc < 8; ++cc) {
                float v = Vs[tx + cc * 16][k];
                O[0][cc] += pv0 * v;
                O[1][cc] += pv1 * v;
            }
        }
        __syncthreads();   // before next tile overwrites Ks/Vs/Ps
    }

    // normalize, stage into Qs (done with Q), coalesced writeback
    float inv0 = 1.f / l_i[0], inv1 = 1.f / l_i[1];
#pragma unroll
    for (int cc = 0; cc < 8; ++cc) {
        Qs[tx + cc * 16][2 * ty]     = O[0][cc] * inv0;
        Qs[tx + cc * 16][2 * ty + 1] = O[1][cc] * inv1;
    }
    __syncthreads();
    float* an = att + (size_t)n * CH * HW;
#pragma unroll
    for (int l = 0; l < 16; ++l) {
        int elem = l * 256 + tid;
        int c = elem >> 5, q = elem & 31;
        an[(size_t)c * HW + q0 + q] = Qs[c][q];
    }
}

// ---------------------------------------------------------------------------
// Kernel 3: z = Z_w @ att[n], BN (inference), + residual x.
// Same GEMM structure as kernel 1, K = 128.
// ---------------------------------------------------------------------------
__global__ __launch_bounds__(256) void zbn_kernel(const float* __restrict__ att,
                                                  const float* __restrict__ Zw,
                                                  const float* __restrict__ gamma,
                                                  const float* __restrict__ beta,
                                                  const float* __restrict__ mean,
                                                  const float* __restrict__ var,
                                                  const float* __restrict__ x,
                                                  float* __restrict__ out) {
    const int n  = blockIdx.z;
    const int m0 = blockIdx.y * 64;   // over 512
    const int q0 = blockIdx.x * 64;   // over 3136
    const int tid = threadIdx.x;
    const int tx = tid & 15, ty = tid >> 4;

    __shared__ float As[16][65];   // [k][m]
    __shared__ float Bs[16][65];   // [k][q]

    float acc[4][4] = {};
    const float* an = att + (size_t)n * CH * HW;

    for (int k0 = 0; k0 < CH; k0 += 16) {
#pragma unroll
        for (int l = 0; l < 4; ++l) {
            int elem = l * 256 + tid;
            int m = elem >> 4, k = elem & 15;
            As[k][m] = Zw[(size_t)(m0 + m) * CH + k0 + k];
        }
#pragma unroll
        for (int l = 0; l < 4; ++l) {
            int elem = l * 256 + tid;
            int k = elem >> 6, q = elem & 63;
            Bs[k][q] = an[(size_t)(k0 + k) * HW + q0 + q];
        }
        __syncthreads();
#pragma unroll
        for (int k = 0; k < 16; ++k) {
            float a[4], b[4];
#pragma unroll
            for (int i = 0; i < 4; ++i) a[i] = As[k][i * 16 + ty];
#pragma unroll
            for (int j = 0; j < 4; ++j) b[j] = Bs[k][j * 16 + tx];
#pragma unroll
            for (int i = 0; i < 4; ++i)
#pragma unroll
                for (int j = 0; j < 4; ++j) acc[i][j] += a[i] * b[j];
        }
        __syncthreads();
    }

#pragma unroll
    for (int i = 0; i < 4; ++i) {
        int m = m0 + i * 16 + ty;
        float inv = gamma[m] * rsqrtf(var[m] + BNEPS);
        float add = beta[m] - mean[m] * inv;
#pragma unroll
        for (int j = 0; j < 4; ++j) {
            size_t idx = (size_t)n * CIN * HW + (size_t)m * HW + q0 + j * 16 + tx;
            out[idx] = acc[i][j] * inv + add + x[idx];
        }
    }
}

// ---------------------------------------------------------------------------
extern "C" void kernel_launch(void* const* d_in, const int* in_sizes, int n_in,
                              void* d_out, int out_size, void* d_ws, size_t ws_size,
                              hipStream_t stream) {
    const float* x     = (const float*)d_in[0];
    const float* Ww    = (const float*)d_in[1];
    const float* Wb    = (const float*)d_in[2];
    const float* Zw    = (const float*)d_in[3];
    const float* gamma = (const float*)d_in[4];
    const float* beta  = (const float*)d_in[5];
    const float* mean  = (const float*)d_in[6];
    const float* var   = (const float*)d_in[7];
    float* out = (float*)d_out;

    const size_t n_tpg = (size_t)NB * TCH * HW;   // 9,633,792 floats
    const size_t n_att = (size_t)NB * CH * HW;    // 3,211,264 floats

    float* tpg;
    float* att;
    if (ws_size >= (n_tpg + n_att) * sizeof(float)) {
        tpg = (float*)d_ws;
        att = tpg + n_tpg;
    } else {
        // fallback: stage t/p/g in d_out (fully overwritten by zbn at the end),
        // att in the workspace (needs only ~12.8 MB)
        tpg = out;
        att = (float*)d_ws;
    }

    proj_kernel<<<dim3(HW / 64, TCH / 64, NB), 256, 0, stream>>>(x, Ww, Wb, tpg);
    attn_kernel<<<dim3(HW / 32, NB), 256, 0, stream>>>(tpg, att);
    zbn_kernel<<<dim3(HW / 64, CIN / 64, NB), 256, 0, stream>>>(att, Zw, gamma, beta,
                                                                mean, var, x, out);
}

// Round 2
// 404.029 us; speedup vs baseline: 6.2099x; 6.2099x over previous
//
#include <hip/hip_runtime.h>
#include <hip/hip_bf16.h>
#include <math.h>

// Problem constants
#define NB    8          // batch
#define CIN   512        // in channels
#define HW    3136       // 56*56
#define CH    128        // attention channels
#define TCH   384        // 3*CH
#define SCALE 0.08838834764831845f   // 128^-0.5
#define BNEPS 1e-5f

typedef __attribute__((ext_vector_type(8))) short bf16x8;   // 8 bf16 (4 VGPRs)
typedef __attribute__((ext_vector_type(4))) float f32x4;    // MFMA accumulator

#define MFMA16(a, b, c) __builtin_amdgcn_mfma_f32_16x16x32_bf16((a), (b), (c), 0, 0, 0)

// ---------------------------------------------------------------------------
// Kernel 1: proj = W_w @ x[n] + b, written as bf16:
//   m in [0,128)   -> Qt[n][q][c]   (transposed, q-major)
//   m in [128,256) -> Kt[n][k][c]   (transposed, k-major)
//   m in [256,384) -> Vg[n][c][q]   (as computed, c-major)
// f32 GEMM core identical to round 1 (it was ~roofline); new epilogue stages
// the 64x64 tile through a XOR-swizzled LDS buffer for coalesced bf16 writes.
// ---------------------------------------------------------------------------
__global__ __launch_bounds__(256) void proj_kernel(const float* __restrict__ x,
                                                   const float* __restrict__ Ww,
                                                   const float* __restrict__ Wb,
                                                   __hip_bfloat16* __restrict__ Qt,
                                                   __hip_bfloat16* __restrict__ Kt,
                                                   __hip_bfloat16* __restrict__ Vg) {
    const int n  = blockIdx.z;
    const int m0 = blockIdx.y * 64;   // over 384
    const int q0 = blockIdx.x * 64;   // over 3136
    const int tid = threadIdx.x;
    const int tx = tid & 15, ty = tid >> 4;

    __shared__ float As[16][65];   // [k][m]
    __shared__ float Bs[16][65];   // [k][q]
    __shared__ char  Ts[64 * 128]; // 64 rows x 128B (64 bf16), XOR-swizzled

    float acc[4][4] = {};
    const float* xn = x + (size_t)n * CIN * HW;

    for (int k0 = 0; k0 < CIN; k0 += 16) {
#pragma unroll
        for (int l = 0; l < 4; ++l) {          // A tile: 64m x 16k
            int elem = l * 256 + tid;
            int m = elem >> 4, k = elem & 15;
            As[k][m] = Ww[(size_t)(m0 + m) * CIN + k0 + k];
        }
#pragma unroll
        for (int l = 0; l < 4; ++l) {          // B tile: 16k x 64q
            int elem = l * 256 + tid;
            int k = elem >> 6, q = elem & 63;
            Bs[k][q] = xn[(size_t)(k0 + k) * HW + q0 + q];
        }
        __syncthreads();
#pragma unroll
        for (int k = 0; k < 16; ++k) {
            float a[4], b[4];
#pragma unroll
            for (int i = 0; i < 4; ++i) a[i] = As[k][i * 16 + ty];
#pragma unroll
            for (int j = 0; j < 4; ++j) b[j] = Bs[k][j * 16 + tx];
#pragma unroll
            for (int i = 0; i < 4; ++i)
#pragma unroll
                for (int j = 0; j < 4; ++j) acc[i][j] += a[i] * b[j];
        }
        __syncthreads();
    }

    const int region = m0 >> 7;     // 0=Q, 1=K, 2=V
    const int c0     = m0 & 127;    // 0 or 64

    // stage tile into Ts (row-major [row][64 bf16], byte ^= ((row&7)<<4))
#pragma unroll
    for (int i = 0; i < 4; ++i) {
        float bias = Wb[m0 + i * 16 + ty];
#pragma unroll
        for (int j = 0; j < 4; ++j) {
            __hip_bfloat16 v = __float2bfloat16(acc[i][j] + bias);
            int row, colb;
            if (region < 2) { row = j * 16 + tx; colb = (i * 16 + ty) * 2; }  // [q][m]
            else            { row = i * 16 + ty; colb = (j * 16 + tx) * 2; }  // [m][q]
            *(__hip_bfloat16*)(Ts + row * 128 + (colb ^ ((row & 7) << 4))) = v;
        }
    }
    __syncthreads();

    __hip_bfloat16* base;
    size_t rstride;
    if (region == 0)      { base = Qt + (size_t)n * HW * CH + (size_t)q0 * CH + c0; rstride = CH; }
    else if (region == 1) { base = Kt + (size_t)n * HW * CH + (size_t)q0 * CH + c0; rstride = CH; }
    else                  { base = Vg + (size_t)n * CH * HW + (size_t)c0 * HW + q0; rstride = HW; }

    // 64 rows x 8 chunks(16B) = 512 chunks; 2 per thread
#pragma unroll
    for (int it = 0; it < 2; ++it) {
        int ch = it * 256 + tid;
        int rr = ch >> 3, o = ch & 7;
        bf16x8 v = *(const bf16x8*)(Ts + rr * 128 + ((o * 16) ^ ((rr & 7) << 4)));
        *(bf16x8*)(base + (size_t)rr * rstride + o * 8) = v;
    }
}

// ---------------------------------------------------------------------------
// Kernel 2: flash attention, bf16 MFMA (16x16x32), f32 accumulate.
//   S = Q K^T * SCALE (online softmax), att[c][q] = (softmax(S) V)[q][c]
// Block: 256 threads = 4 waves; QBLK=64 (wave w owns q rows [16w,16w+16)),
// KVBLK=64. LDS: Ks[64][128c]bf16 + Vt[128][64v]bf16 (+Ps 16x64 per wave),
// all XOR-swizzled (byte ^= ((row&7)<<4)) to kill frag-read bank conflicts.
// ---------------------------------------------------------------------------
__global__ __launch_bounds__(256, 2) void attn_kernel(
        const __hip_bfloat16* __restrict__ Qt,   // [NB][HW][CH]
        const __hip_bfloat16* __restrict__ Kt,   // [NB][HW][CH]
        const __hip_bfloat16* __restrict__ Vg,   // [NB][CH][HW]
        float* __restrict__ att) {               // [NB][CH][HW]
    const int n  = blockIdx.y;
    const int q0 = blockIdx.x * 64;
    const int tid  = threadIdx.x;
    const int lane = tid & 63, wv = tid >> 6;
    const int lr = lane & 15, hi = lane >> 4;

    __shared__ char smem[40960];
    char* Ks = smem;                       // 64 rows * 256B  (k-major, c contiguous)
    char* Vt = smem + 16384;               // 128 rows * 128B (c-major, v contiguous)
    char* Ps = smem + 32768 + wv * 2048;   // 16 rows * 128B per wave

    const __hip_bfloat16* Qg = Qt + ((size_t)n * HW + q0) * CH;
    const __hip_bfloat16* Kg = Kt + (size_t)n * HW * CH;
    const __hip_bfloat16* Vp = Vg + (size_t)n * CH * HW;

    // ---- stage Q (64x128 bf16) into Ks region, load A-frags to registers
#pragma unroll
    for (int it = 0; it < 4; ++it) {
        int ch = it * 256 + tid, r = ch >> 4, o = ch & 15;
        bf16x8 v = *(const bf16x8*)(Qg + (size_t)r * CH + o * 8);
        *(bf16x8*)(Ks + r * 256 + ((o * 16) ^ ((r & 7) << 4))) = v;
    }
    __syncthreads();
    const int qrow = wv * 16 + lr;
    bf16x8 qf[4];
#pragma unroll
    for (int cs = 0; cs < 4; ++cs)
        qf[cs] = *(const bf16x8*)(Ks + qrow * 256 + ((cs * 64 + hi * 16) ^ ((qrow & 7) << 4)));
    __syncthreads();

    f32x4 O[8] = {};                       // rows hi*4+reg, cols cn*16+lr
    float m_i[4] = {-1e30f, -1e30f, -1e30f, -1e30f};
    float l_i[4] = {0.f, 0.f, 0.f, 0.f};

    for (int k0 = 0; k0 < HW; k0 += 64) {
        // stage K tile [64][128] bf16
#pragma unroll
        for (int it = 0; it < 4; ++it) {
            int ch = it * 256 + tid, r = ch >> 4, o = ch & 15;
            bf16x8 v = *(const bf16x8*)(Kg + (size_t)(k0 + r) * CH + o * 8);
            *(bf16x8*)(Ks + r * 256 + ((o * 16) ^ ((r & 7) << 4))) = v;
        }
        // stage V tile [128][64] bf16 (rows of Vg, no transpose needed)
#pragma unroll
        for (int it = 0; it < 4; ++it) {
            int ch = it * 256 + tid, c = ch >> 3, o = ch & 7;
            bf16x8 v = *(const bf16x8*)(Vp + (size_t)c * HW + k0 + o * 8);
            *(bf16x8*)(Vt + c * 128 + ((o * 16) ^ ((c & 7) << 4))) = v;
        }
        __syncthreads();

        // S = Q K^T : sacc[kn] covers cols kn*16..+16, rows = wave's 16 q
        f32x4 sacc[4] = {};
#pragma unroll
        for (int kn = 0; kn < 4; ++kn) {
            int krow = kn * 16 + lr;
#pragma unroll
            for (int cs = 0; cs < 4; ++cs) {
                bf16x8 kf = *(const bf16x8*)(Ks + krow * 256 +
                                             ((cs * 64 + hi * 16) ^ ((krow & 7) << 4)));
                sacc[kn] = MFMA16(qf[cs], kf, sacc[kn]);
            }
        }

        // online softmax (raw-s max tracking; SCALE applied in the exponent)
        float pp[4][4];
#pragma unroll
        for (int reg = 0; reg < 4; ++reg) {
            float mx = fmaxf(fmaxf(sacc[0][reg], sacc[1][reg]),
                             fmaxf(sacc[2][reg], sacc[3][reg]));
#pragma unroll
            for (int off = 1; off < 16; off <<= 1) mx = fmaxf(mx, __shfl_xor(mx, off));
            float nm = fmaxf(m_i[reg], mx);
            float f  = __expf((m_i[reg] - nm) * SCALE);
            float rs = 0.f;
#pragma unroll
            for (int kn = 0; kn < 4; ++kn) {
                pp[kn][reg] = __expf((sacc[kn][reg] - nm) * SCALE);
                rs += pp[kn][reg];
            }
#pragma unroll
            for (int off = 1; off < 16; off <<= 1) rs += __shfl_xor(rs, off);
            l_i[reg] = l_i[reg] * f + rs;
            m_i[reg] = nm;
#pragma unroll
            for (int cn = 0; cn < 8; ++cn) O[cn][reg] *= f;
        }

        // P -> bf16 -> per-wave LDS (rows r=hi*4+reg, cols kn*16+lr)
#pragma unroll
        for (int kn = 0; kn < 4; ++kn)
#pragma unroll
            for (int reg = 0; reg < 4; ++reg) {
                int r = hi * 4 + reg, colb = (kn * 16 + lr) * 2;
                *(__hip_bfloat16*)(Ps + r * 128 + (colb ^ ((r & 7) << 4))) =
                    __float2bfloat16(pp[kn][reg]);
            }

        // O += P V : A-frag from Ps (row lr), B-frag from Vt (row cn*16+lr)
#pragma unroll
        for (int ks = 0; ks < 2; ++ks) {
            bf16x8 pa = *(const bf16x8*)(Ps + lr * 128 +
                                         ((ks * 64 + hi * 16) ^ ((lr & 7) << 4)));
#pragma unroll
            for (int cn = 0; cn < 8; ++cn) {
                int vr = cn * 16 + lr;
                bf16x8 vb = *(const bf16x8*)(Vt + vr * 128 +
                                             ((ks * 64 + hi * 16) ^ ((vr & 7) << 4)));
                O[cn] = MFMA16(pa, vb, O[cn]);
            }
        }
        __syncthreads();   // all waves done with Ks/Vt before restage
    }

    // normalize, stage O as [c][q] f32 (overlays Ks+Vt), coalesced writeback
#pragma unroll
    for (int reg = 0; reg < 4; ++reg) {
        float inv = 1.f / l_i[reg];
#pragma unroll
        for (int cn = 0; cn < 8; ++cn) O[cn][reg] *= inv;
    }
#pragma unroll
    for (int cn = 0; cn < 8; ++cn) {
        int c = cn * 16 + lr;
        *(f32x4*)(smem + c * 256 + ((wv * 64 + hi * 16) ^ ((c & 7) << 4))) = O[cn];
    }
    __syncthreads();
    float* ag = att + (size_t)n * CH * HW + q0;
#pragma unroll
    for (int it = 0; it < 8; ++it) {
        int ch = it * 256 + tid, c = ch >> 4, o = ch & 15;
        f32x4 v = *(const f32x4*)(smem + c * 256 + ((o * 16) ^ ((c & 7) << 4)));
        *(f32x4*)(ag + (size_t)c * HW + o * 4) = v;
    }
}

// ---------------------------------------------------------------------------
// Kernel 3: z = Z_w @ att[n], BN (inference), + residual x. Unchanged (f32).
// ---------------------------------------------------------------------------
__global__ __launch_bounds__(256) void zbn_kernel(const float* __restrict__ att,
                                                  const float* __restrict__ Zw,
                                                  const float* __restrict__ gamma,
                                                  const float* __restrict__ beta,
                                                  const float* __restrict__ mean,
                                                  const float* __restrict__ var,
                                                  const float* __restrict__ x,
                                                  float* __restrict__ out) {
    const int n  = blockIdx.z;
    const int m0 = blockIdx.y * 64;   // over 512
    const int q0 = blockIdx.x * 64;   // over 3136
    const int tid = threadIdx.x;
    const int tx = tid & 15, ty = tid >> 4;

    __shared__ float As[16][65];   // [k][m]
    __shared__ float Bs[16][65];   // [k][q]

    float acc[4][4] = {};
    const float* an = att + (size_t)n * CH * HW;

    for (int k0 = 0; k0 < CH; k0 += 16) {
#pragma unroll
        for (int l = 0; l < 4; ++l) {
            int elem = l * 256 + tid;
            int m = elem >> 4, k = elem & 15;
            As[k][m] = Zw[(size_t)(m0 + m) * CH + k0 + k];
        }
#pragma unroll
        for (int l = 0; l < 4; ++l) {
            int elem = l * 256 + tid;
            int k = elem >> 6, q = elem & 63;
            Bs[k][q] = an[(size_t)(k0 + k) * HW + q0 + q];
        }
        __syncthreads();
#pragma unroll
        for (int k = 0; k < 16; ++k) {
            float a[4], b[4];
#pragma unroll
            for (int i = 0; i < 4; ++i) a[i] = As[k][i * 16 + ty];
#pragma unroll
            for (int j = 0; j < 4; ++j) b[j] = Bs[k][j * 16 + tx];
#pragma unroll
            for (int i = 0; i < 4; ++i)
#pragma unroll
                for (int j = 0; j < 4; ++j) acc[i][j] += a[i] * b[j];
        }
        __syncthreads();
    }

#pragma unroll
    for (int i = 0; i < 4; ++i) {
        int m = m0 + i * 16 + ty;
        float inv = gamma[m] * rsqrtf(var[m] + BNEPS);
        float add = beta[m] - mean[m] * inv;
#pragma unroll
        for (int j = 0; j < 4; ++j) {
            size_t idx = (size_t)n * CIN * HW + (size_t)m * HW + q0 + j * 16 + tx;
            out[idx] = acc[i][j] * inv + add + x[idx];
        }
    }
}

// ---------------------------------------------------------------------------
extern "C" void kernel_launch(void* const* d_in, const int* in_sizes, int n_in,
                              void* d_out, int out_size, void* d_ws, size_t ws_size,
                              hipStream_t stream) {
    const float* x     = (const float*)d_in[0];
    const float* Ww    = (const float*)d_in[1];
    const float* Wb    = (const float*)d_in[2];
    const float* Zw    = (const float*)d_in[3];
    const float* gamma = (const float*)d_in[4];
    const float* beta  = (const float*)d_in[5];
    const float* mean  = (const float*)d_in[6];
    const float* var   = (const float*)d_in[7];
    float* out = (float*)d_out;

    const size_t n_elem     = (size_t)NB * CH * HW;                 // 3,211,264
    const size_t qkv_bytes  = n_elem * sizeof(__hip_bfloat16);      // 6.42 MB each
    const size_t att_bytes  = n_elem * sizeof(float);               // 12.85 MB

    __hip_bfloat16 *Qt, *Kt, *Vgb;
    float* att;
    if (ws_size >= 3 * qkv_bytes + att_bytes) {
        char* w = (char*)d_ws;
        Qt  = (__hip_bfloat16*)w;
        Kt  = (__hip_bfloat16*)(w + qkv_bytes);
        Vgb = (__hip_bfloat16*)(w + 2 * qkv_bytes);
        att = (float*)(w + 3 * qkv_bytes);
    } else {
        // stage Q/K/V bf16 in d_out (19.3 MB < 51.4 MB, fully overwritten by
        // zbn afterwards), att in workspace (12.85 MB)
        char* w = (char*)d_out;
        Qt  = (__hip_bfloat16*)w;
        Kt  = (__hip_bfloat16*)(w + qkv_bytes);
        Vgb = (__hip_bfloat16*)(w + 2 * qkv_bytes);
        att = (float*)d_ws;
    }

    proj_kernel<<<dim3(HW / 64, TCH / 64, NB), 256, 0, stream>>>(x, Ww, Wb, Qt, Kt, Vgb);
    attn_kernel<<<dim3(HW / 64, NB), 256, 0, stream>>>(Qt, Kt, Vgb, att);
    zbn_kernel<<<dim3(HW / 64, CIN / 64, NB), 256, 0, stream>>>(att, Zw, gamma, beta,
                                                                mean, var, x, out);
}

// Round 3
// 230.787 us; speedup vs baseline: 10.8715x; 1.7507x over previous
//
#include <hip/hip_runtime.h>
#include <hip/hip_bf16.h>
#include <math.h>

// Problem constants
#define NB    8          // batch
#define CIN   512        // in channels
#define HW    3136       // 56*56
#define CH    128        // attention channels
#define TCH   384        // 3*CH
#define SCALE 0.08838834764831845f   // 128^-0.5
#define BNEPS 1e-5f

typedef __attribute__((ext_vector_type(8))) short bf16x8;   // 8 bf16 (4 VGPRs)
typedef __attribute__((ext_vector_type(4))) short bf16x4;   // 4 bf16 (2 VGPRs)
typedef __attribute__((ext_vector_type(4))) float f32x4;    // MFMA accumulator

#define MFMA16(a, b, c) __builtin_amdgcn_mfma_f32_16x16x32_bf16((a), (b), (c), 0, 0, 0)

__device__ inline short f2bf(float f) {
    __hip_bfloat16 h = __float2bfloat16(f);
    return *reinterpret_cast<short*>(&h);
}

// ---------------------------------------------------------------------------
// Kernel 0a: convert Ww (384x512) and Zw (512x128) f32 -> bf16, row-major.
// ---------------------------------------------------------------------------
__global__ __launch_bounds__(256) void cvt_wts(const float* __restrict__ Ww,
                                               const float* __restrict__ Zw,
                                               __hip_bfloat16* __restrict__ WwB,
                                               __hip_bfloat16* __restrict__ ZwB) {
    const int nW = TCH * CIN / 4;   // 49152 float4 chunks
    const int nZ = CIN * CH / 4;    // 16384
    int i = blockIdx.x * 256 + threadIdx.x;
    if (i < nW) {
        float4 v = ((const float4*)Ww)[i];
        bf16x4 o; o[0] = f2bf(v.x); o[1] = f2bf(v.y); o[2] = f2bf(v.z); o[3] = f2bf(v.w);
        ((bf16x4*)WwB)[i] = o;
    } else if (i < nW + nZ) {
        int j = i - nW;
        float4 v = ((const float4*)Zw)[j];
        bf16x4 o; o[0] = f2bf(v.x); o[1] = f2bf(v.y); o[2] = f2bf(v.z); o[3] = f2bf(v.w);
        ((bf16x4*)ZwB)[j] = o;
    }
}

// ---------------------------------------------------------------------------
// Kernel 0b: xT[n][q][c] bf16 = transpose+cvt of x[n][c][q] f32.
// 64c x 64q tile; 4x4 in-register micro-transpose; LDS swizzle 8B-granular.
// ---------------------------------------------------------------------------
__global__ __launch_bounds__(256) void xpose_kernel(const float* __restrict__ x,
                                                    __hip_bfloat16* __restrict__ xT) {
    const int n = blockIdx.z, c0 = blockIdx.y * 64, q0 = blockIdx.x * 64;
    const int tid = threadIdx.x;
    const int mr = tid >> 4, mq = tid & 15;

    __shared__ char T[64 * 128];   // [q][64 c] bf16, byte ^= ((q&15)<<3)

    const float* xp = x + ((size_t)(n * CIN + c0 + mr * 4)) * HW + q0 + mq * 4;
    float4 r0 = *(const float4*)(xp);
    float4 r1 = *(const float4*)(xp + HW);
    float4 r2 = *(const float4*)(xp + 2 * HW);
    float4 r3 = *(const float4*)(xp + 3 * HW);
    const float* f0 = (const float*)&r0; const float* f1 = (const float*)&r1;
    const float* f2 = (const float*)&r2; const float* f3 = (const float*)&r3;
#pragma unroll
    for (int j = 0; j < 4; ++j) {
        int q = mq * 4 + j;
        bf16x4 v; v[0] = f2bf(f0[j]); v[1] = f2bf(f1[j]);
                  v[2] = f2bf(f2[j]); v[3] = f2bf(f3[j]);
        *(bf16x4*)(T + q * 128 + ((mr * 8) ^ ((q & 15) << 3))) = v;
    }
    __syncthreads();

    __hip_bfloat16* og = xT + ((size_t)n * HW + q0) * CIN + c0;
#pragma unroll
    for (int it = 0; it < 2; ++it) {
        int ch = it * 256 + tid, rr = ch >> 3, o8 = ch & 7;
        int sw = (rr & 15) << 3;
        bf16x4 lo = *(const bf16x4*)(T + rr * 128 + ((o8 * 16) ^ sw));
        bf16x4 hi = *(const bf16x4*)(T + rr * 128 + ((o8 * 16 + 8) ^ sw));
        bf16x8 v; v[0] = lo[0]; v[1] = lo[1]; v[2] = lo[2]; v[3] = lo[3];
                  v[4] = hi[0]; v[5] = hi[1]; v[6] = hi[2]; v[7] = hi[3];
        *(bf16x8*)(og + (size_t)rr * CIN + o8 * 8) = v;
    }
}

// ---------------------------------------------------------------------------
// Kernel 1: proj via MFMA. C[m][q] = sum_c WwB[m][c] * xT[q][c], + bias.
//   m in [0,128)   -> Qt[n][q][c]
//   m in [128,256) -> Kt[n][k][c]
//   m in [256,384) -> Vg[n][c][q]
// 64m x 64q tile, K-chunk 64, 4 waves each owning 16 m-rows.
// ---------------------------------------------------------------------------
__global__ __launch_bounds__(256) void proj_kernel(const __hip_bfloat16* __restrict__ xT,
                                                   const __hip_bfloat16* __restrict__ WwB,
                                                   const float* __restrict__ Wb,
                                                   __hip_bfloat16* __restrict__ Qt,
                                                   __hip_bfloat16* __restrict__ Kt,
                                                   __hip_bfloat16* __restrict__ Vg) {
    const int n  = blockIdx.z;
    const int m0 = blockIdx.y * 64;   // over 384
    const int q0 = blockIdx.x * 64;   // over 3136
    const int tid = threadIdx.x;
    const int lane = tid & 63, wv = tid >> 6;
    const int lr = lane & 15, hi = lane >> 4;

    __shared__ char Aw[64 * 128];  // [m][64 c] bf16, byte ^= ((r&7)<<4)
    __shared__ char Bx[64 * 128];  // [q][64 c]
    __shared__ char Ts[64 * 128];  // epilogue staging

    f32x4 acc[4] = {};
    const __hip_bfloat16* xn = xT + ((size_t)n * HW + q0) * CIN;

    for (int k0 = 0; k0 < CIN; k0 += 64) {
#pragma unroll
        for (int it = 0; it < 2; ++it) {
            int ch = it * 256 + tid, r = ch >> 3, o = ch & 7;
            int sw = (o * 16) ^ ((r & 7) << 4);
            bf16x8 a = *(const bf16x8*)(WwB + (size_t)(m0 + r) * CIN + k0 + o * 8);
            *(bf16x8*)(Aw + r * 128 + sw) = a;
            bf16x8 b = *(const bf16x8*)(xn + (size_t)r * CIN + k0 + o * 8);
            *(bf16x8*)(Bx + r * 128 + sw) = b;
        }
        __syncthreads();

        const int mrow = wv * 16 + lr;
#pragma unroll
        for (int ks = 0; ks < 2; ++ks) {
            bf16x8 af = *(const bf16x8*)(Aw + mrow * 128 +
                                         ((ks * 64 + hi * 16) ^ ((mrow & 7) << 4)));
#pragma unroll
            for (int kn = 0; kn < 4; ++kn) {
                int qrow = kn * 16 + lr;
                bf16x8 bfr = *(const bf16x8*)(Bx + qrow * 128 +
                                              ((ks * 64 + hi * 16) ^ ((qrow & 7) << 4)));
                acc[kn] = MFMA16(af, bfr, acc[kn]);
            }
        }
        __syncthreads();
    }

    const int region = m0 >> 7;     // 0=Q, 1=K, 2=V
    const int c0     = m0 & 127;    // 0 or 64

    float bias[4];
#pragma unroll
    for (int reg = 0; reg < 4; ++reg) bias[reg] = Wb[m0 + wv * 16 + hi * 4 + reg];

    // stage tile into Ts: Q/K as [q][m-local], V as [m-local][q]
#pragma unroll
    for (int kn = 0; kn < 4; ++kn)
#pragma unroll
        for (int reg = 0; reg < 4; ++reg) {
            __hip_bfloat16 v = __float2bfloat16(acc[kn][reg] + bias[reg]);
            int row, colb;
            if (region < 2) { row = kn * 16 + lr; colb = (wv * 16 + hi * 4 + reg) * 2; }
            else            { row = wv * 16 + hi * 4 + reg; colb = (kn * 16 + lr) * 2; }
            *(__hip_bfloat16*)(Ts + row * 128 + (colb ^ ((row & 7) << 4))) = v;
        }
    __syncthreads();

    __hip_bfloat16* base;
    size_t rstride;
    if (region == 0)      { base = Qt + (size_t)n * HW * CH + (size_t)q0 * CH + c0; rstride = CH; }
    else if (region == 1) { base = Kt + (size_t)n * HW * CH + (size_t)q0 * CH + c0; rstride = CH; }
    else                  { base = Vg + (size_t)n * CH * HW + (size_t)c0 * HW + q0; rstride = HW; }

#pragma unroll
    for (int it = 0; it < 2; ++it) {
        int ch = it * 256 + tid, rr = ch >> 3, o = ch & 7;
        bf16x8 v = *(const bf16x8*)(Ts + rr * 128 + ((o * 16) ^ ((rr & 7) << 4)));
        *(bf16x8*)(base + (size_t)rr * rstride + o * 8) = v;
    }
}

// ---------------------------------------------------------------------------
// Kernel 2: flash attention, bf16 MFMA. Writes att as bf16 [n][q][c].
// ---------------------------------------------------------------------------
__global__ __launch_bounds__(256, 2) void attn_kernel(
        const __hip_bfloat16* __restrict__ Qt,   // [NB][HW][CH]
        const __hip_bfloat16* __restrict__ Kt,   // [NB][HW][CH]
        const __hip_bfloat16* __restrict__ Vg,   // [NB][CH][HW]
        __hip_bfloat16* __restrict__ att) {      // [NB][HW][CH]
    const int n  = blockIdx.y;
    const int q0 = blockIdx.x * 64;
    const int tid  = threadIdx.x;
    const int lane = tid & 63, wv = tid >> 6;
    const int lr = lane & 15, hi = lane >> 4;

    __shared__ char smem[40960];
    char* Ks = smem;                       // 64 rows * 256B  (k-major, c contiguous)
    char* Vt = smem + 16384;               // 128 rows * 128B (c-major, v contiguous)
    char* Ps = smem + 32768 + wv * 2048;   // 16 rows * 128B per wave

    const __hip_bfloat16* Qg = Qt + ((size_t)n * HW + q0) * CH;
    const __hip_bfloat16* Kg = Kt + (size_t)n * HW * CH;
    const __hip_bfloat16* Vp = Vg + (size_t)n * CH * HW;

    // ---- stage Q (64x128 bf16) into Ks region, load A-frags to registers
#pragma unroll
    for (int it = 0; it < 4; ++it) {
        int ch = it * 256 + tid, r = ch >> 4, o = ch & 15;
        bf16x8 v = *(const bf16x8*)(Qg + (size_t)r * CH + o * 8);
        *(bf16x8*)(Ks + r * 256 + ((o * 16) ^ ((r & 7) << 4))) = v;
    }
    __syncthreads();
    const int qrow = wv * 16 + lr;
    bf16x8 qf[4];
#pragma unroll
    for (int cs = 0; cs < 4; ++cs)
        qf[cs] = *(const bf16x8*)(Ks + qrow * 256 + ((cs * 64 + hi * 16) ^ ((qrow & 7) << 4)));
    __syncthreads();

    f32x4 O[8] = {};                       // rows hi*4+reg (q), cols cn*16+lr (c)
    float m_i[4] = {-1e30f, -1e30f, -1e30f, -1e30f};
    float l_i[4] = {0.f, 0.f, 0.f, 0.f};

    for (int k0 = 0; k0 < HW; k0 += 64) {
        // stage K tile [64][128] bf16
#pragma unroll
        for (int it = 0; it < 4; ++it) {
            int ch = it * 256 + tid, r = ch >> 4, o = ch & 15;
            bf16x8 v = *(const bf16x8*)(Kg + (size_t)(k0 + r) * CH + o * 8);
            *(bf16x8*)(Ks + r * 256 + ((o * 16) ^ ((r & 7) << 4))) = v;
        }
        // stage V tile [128][64] bf16
#pragma unroll
        for (int it = 0; it < 4; ++it) {
            int ch = it * 256 + tid, c = ch >> 3, o = ch & 7;
            bf16x8 v = *(const bf16x8*)(Vp + (size_t)c * HW + k0 + o * 8);
            *(bf16x8*)(Vt + c * 128 + ((o * 16) ^ ((c & 7) << 4))) = v;
        }
        __syncthreads();

        // S = Q K^T
        f32x4 sacc[4] = {};
#pragma unroll
        for (int kn = 0; kn < 4; ++kn) {
            int krow = kn * 16 + lr;
#pragma unroll
            for (int cs = 0; cs < 4; ++cs) {
                bf16x8 kf = *(const bf16x8*)(Ks + krow * 256 +
                                             ((cs * 64 + hi * 16) ^ ((krow & 7) << 4)));
                sacc[kn] = MFMA16(qf[cs], kf, sacc[kn]);
            }
        }

        // online softmax
        float pp[4][4];
#pragma unroll
        for (int reg = 0; reg < 4; ++reg) {
            float mx = fmaxf(fmaxf(sacc[0][reg], sacc[1][reg]),
                             fmaxf(sacc[2][reg], sacc[3][reg]));
#pragma unroll
            for (int off = 1; off < 16; off <<= 1) mx = fmaxf(mx, __shfl_xor(mx, off));
            float nm = fmaxf(m_i[reg], mx);
            float f  = __expf((m_i[reg] - nm) * SCALE);
            float rs = 0.f;
#pragma unroll
            for (int kn = 0; kn < 4; ++kn) {
                pp[kn][reg] = __expf((sacc[kn][reg] - nm) * SCALE);
                rs += pp[kn][reg];
            }
#pragma unroll
            for (int off = 1; off < 16; off <<= 1) rs += __shfl_xor(rs, off);
            l_i[reg] = l_i[reg] * f + rs;
            m_i[reg] = nm;
#pragma unroll
            for (int cn = 0; cn < 8; ++cn) O[cn][reg] *= f;
        }

        // P -> bf16 -> per-wave LDS
#pragma unroll
        for (int kn = 0; kn < 4; ++kn)
#pragma unroll
            for (int reg = 0; reg < 4; ++reg) {
                int r = hi * 4 + reg, colb = (kn * 16 + lr) * 2;
                *(__hip_bfloat16*)(Ps + r * 128 + (colb ^ ((r & 7) << 4))) =
                    __float2bfloat16(pp[kn][reg]);
            }

        // O += P V
#pragma unroll
        for (int ks = 0; ks < 2; ++ks) {
            bf16x8 pa = *(const bf16x8*)(Ps + lr * 128 +
                                         ((ks * 64 + hi * 16) ^ ((lr & 7) << 4)));
#pragma unroll
            for (int cn = 0; cn < 8; ++cn) {
                int vr = cn * 16 + lr;
                bf16x8 vb = *(const bf16x8*)(Vt + vr * 128 +
                                             ((ks * 64 + hi * 16) ^ ((vr & 7) << 4)));
                O[cn] = MFMA16(pa, vb, O[cn]);
            }
        }
        __syncthreads();
    }

    // normalize, stage as bf16 [q_local][c] (64 rows x 256B), coalesced writeback
#pragma unroll
    for (int reg = 0; reg < 4; ++reg) {
        float inv = 1.f / l_i[reg];
#pragma unroll
        for (int cn = 0; cn < 8; ++cn) O[cn][reg] *= inv;
    }
#pragma unroll
    for (int cn = 0; cn < 8; ++cn)
#pragma unroll
        for (int reg = 0; reg < 4; ++reg) {
            int row = wv * 16 + hi * 4 + reg, colb = (cn * 16 + lr) * 2;
            *(__hip_bfloat16*)(smem + row * 256 + (colb ^ ((row & 7) << 4))) =
                __float2bfloat16(O[cn][reg]);
        }
    __syncthreads();
    __hip_bfloat16* ag = att + ((size_t)n * HW + q0) * CH;
#pragma unroll
    for (int it = 0; it < 4; ++it) {
        int ch = it * 256 + tid, r = ch >> 4, o = ch & 15;
        bf16x8 v = *(const bf16x8*)(smem + r * 256 + ((o * 16) ^ ((r & 7) << 4)));
        *(bf16x8*)(ag + (size_t)r * CH + o * 8) = v;
    }
}

// ---------------------------------------------------------------------------
// Kernel 3: z = ZwB @ att[n] via MFMA (K=128, single stage), BN + residual.
// 64m x 64q tile, 4 waves x 16 m-rows.
// ---------------------------------------------------------------------------
__global__ __launch_bounds__(256) void zbn_kernel(const __hip_bfloat16* __restrict__ att,
                                                  const __hip_bfloat16* __restrict__ ZwB,
                                                  const float* __restrict__ gamma,
                                                  const float* __restrict__ beta,
                                                  const float* __restrict__ mean,
                                                  const float* __restrict__ var,
                                                  const float* __restrict__ x,
                                                  float* __restrict__ out) {
    const int n  = blockIdx.z;
    const int m0 = blockIdx.y * 64;   // over 512
    const int q0 = blockIdx.x * 64;   // over 3136
    const int tid = threadIdx.x;
    const int lane = tid & 63, wv = tid >> 6;
    const int lr = lane & 15, hi = lane >> 4;

    __shared__ char smem[32768];
    char* Az = smem;            // [m][128 c] bf16, 64 rows * 256B, swizzled
    char* Ba = smem + 16384;    // [q][128 c] bf16

    // stage A (Zw) and B (att), K = 128 in one shot
#pragma unroll
    for (int it = 0; it < 4; ++it) {
        int ch = it * 256 + tid, r = ch >> 4, o = ch & 15;
        int sw = (o * 16) ^ ((r & 7) << 4);
        bf16x8 a = *(const bf16x8*)(ZwB + (size_t)(m0 + r) * CH + o * 8);
        *(bf16x8*)(Az + r * 256 + sw) = a;
        bf16x8 b = *(const bf16x8*)(att + ((size_t)n * HW + q0 + r) * CH + o * 8);
        *(bf16x8*)(Ba + r * 256 + sw) = b;
    }
    __syncthreads();

    f32x4 acc[4] = {};
    const int mrow = wv * 16 + lr;
#pragma unroll
    for (int ks = 0; ks < 4; ++ks) {
        bf16x8 af = *(const bf16x8*)(Az + mrow * 256 +
                                     ((ks * 64 + hi * 16) ^ ((mrow & 7) << 4)));
#pragma unroll
        for (int kn = 0; kn < 4; ++kn) {
            int qrow = kn * 16 + lr;
            bf16x8 bfr = *(const bf16x8*)(Ba + qrow * 256 +
                                          ((ks * 64 + hi * 16) ^ ((qrow & 7) << 4)));
            acc[kn] = MFMA16(af, bfr, acc[kn]);
        }
    }
    __syncthreads();   // smem reused for epilogue staging

    // BN coefficients per m-row
    float inv[4], add[4];
#pragma unroll
    for (int reg = 0; reg < 4; ++reg) {
        int m = m0 + wv * 16 + hi * 4 + reg;
        inv[reg] = gamma[m] * rsqrtf(var[m] + BNEPS);
        add[reg] = beta[m] - mean[m] * inv[reg];
    }

    // stage z tile [m-local][64 q] f32 (256B rows, swizzled)
#pragma unroll
    for (int kn = 0; kn < 4; ++kn)
#pragma unroll
        for (int reg = 0; reg < 4; ++reg) {
            int row = wv * 16 + hi * 4 + reg;
            int colb = (kn * 16 + lr) * 4;
            *(float*)(smem + row * 256 + (colb ^ ((row & 7) << 4))) =
                acc[kn][reg] * inv[reg] + add[reg];
        }
    __syncthreads();

    // coalesced residual add + writeback
#pragma unroll
    for (int it = 0; it < 4; ++it) {
        int ch = it * 256 + tid, rr = ch >> 4, o = ch & 15;
        f32x4 v = *(const f32x4*)(smem + rr * 256 + ((o * 16) ^ ((rr & 7) << 4)));
        size_t idx = (size_t)n * CIN * HW + (size_t)(m0 + rr) * HW + q0 + o * 4;
        float4 xv = *(const float4*)(x + idx);
        float4 ov; ov.x = v[0] + xv.x; ov.y = v[1] + xv.y;
                   ov.z = v[2] + xv.z; ov.w = v[3] + xv.w;
        *(float4*)(out + idx) = ov;
    }
}

// ---------------------------------------------------------------------------
extern "C" void kernel_launch(void* const* d_in, const int* in_sizes, int n_in,
                              void* d_out, int out_size, void* d_ws, size_t ws_size,
                              hipStream_t stream) {
    const float* x     = (const float*)d_in[0];
    const float* Ww    = (const float*)d_in[1];
    const float* Wb    = (const float*)d_in[2];
    const float* Zw    = (const float*)d_in[3];
    const float* gamma = (const float*)d_in[4];
    const float* beta  = (const float*)d_in[5];
    const float* mean  = (const float*)d_in[6];
    const float* var   = (const float*)d_in[7];
    float* out = (float*)d_out;

    const size_t xT_bytes  = (size_t)NB * HW * CIN * 2;   // 25,690,112
    const size_t qkv_bytes = (size_t)NB * HW * CH * 2;    //  6,422,528 each
    const size_t att_bytes = qkv_bytes;
    const size_t WwB_bytes = (size_t)TCH * CIN * 2;       //    393,216
    const size_t ZwB_bytes = (size_t)CIN * CH * 2;        //    131,072
    const size_t total = xT_bytes + 3 * qkv_bytes + att_bytes + WwB_bytes + ZwB_bytes;

    __hip_bfloat16 *xT, *Qt, *Kt, *Vgb, *attb, *WwB, *ZwB;
    if (ws_size >= total) {
        char* w = (char*)d_ws;
        xT   = (__hip_bfloat16*)w;                          w += xT_bytes;
        Qt   = (__hip_bfloat16*)w;                          w += qkv_bytes;
        Kt   = (__hip_bfloat16*)w;                          w += qkv_bytes;
        Vgb  = (__hip_bfloat16*)w;                          w += qkv_bytes;
        attb = (__hip_bfloat16*)w;                          w += att_bytes;
        WwB  = (__hip_bfloat16*)w;                          w += WwB_bytes;
        ZwB  = (__hip_bfloat16*)w;
    } else {
        // d_out (51.4 MB) stages xT + Q/K/V (45 MB, fully overwritten by zbn at
        // the end); workspace holds att + converted weights (~7 MB).
        char* w = (char*)d_out;
        xT   = (__hip_bfloat16*)w;                          w += xT_bytes;
        Qt   = (__hip_bfloat16*)w;                          w += qkv_bytes;
        Kt   = (__hip_bfloat16*)w;                          w += qkv_bytes;
        Vgb  = (__hip_bfloat16*)w;
        char* v = (char*)d_ws;
        attb = (__hip_bfloat16*)v;                          v += att_bytes;
        WwB  = (__hip_bfloat16*)v;                          v += WwB_bytes;
        ZwB  = (__hip_bfloat16*)v;
    }

    cvt_wts<<<dim3(256), 256, 0, stream>>>(Ww, Zw, WwB, ZwB);
    xpose_kernel<<<dim3(HW / 64, CIN / 64, NB), 256, 0, stream>>>(x, xT);
    proj_kernel<<<dim3(HW / 64, TCH / 64, NB), 256, 0, stream>>>(xT, WwB, Wb, Qt, Kt, Vgb);
    attn_kernel<<<dim3(HW / 64, NB), 256, 0, stream>>>(Qt, Kt, Vgb, attb);
    zbn_kernel<<<dim3(HW / 64, CIN / 64, NB), 256, 0, stream>>>(attb, ZwB, gamma, beta,
                                                                mean, var, x, out);
}

// Round 4
// 168.581 us; speedup vs baseline: 14.8830x; 1.3690x over previous
//
#include <hip/hip_runtime.h>
#include <hip/hip_bf16.h>
#include <math.h>

// Problem constants
#define NB    8          // batch
#define CIN   512        // in channels
#define HW    3136       // 56*56
#define CH    128        // attention channels
#define TCH   384        // 3*CH
#define SCALE 0.08838834764831845f   // 128^-0.5
#define BNEPS 1e-5f

typedef __attribute__((ext_vector_type(8))) short bf16x8;   // 8 bf16 (4 VGPRs)
typedef __attribute__((ext_vector_type(4))) short bf16x4;   // 4 bf16 (2 VGPRs)
typedef __attribute__((ext_vector_type(4))) float f32x4;    // MFMA accumulator

#define MFMA16(a, b, c) __builtin_amdgcn_mfma_f32_16x16x32_bf16((a), (b), (c), 0, 0, 0)

__device__ inline short f2bf(float f) {
    __hip_bfloat16 h = __float2bfloat16(f);
    return *reinterpret_cast<short*>(&h);
}
__device__ inline unsigned pack2bf(float a, float b) {
    return (unsigned)(unsigned short)f2bf(a) | ((unsigned)(unsigned short)f2bf(b) << 16);
}

// ---------------------------------------------------------------------------
// Kernel 0a: convert Ww (384x512) and Zw (512x128) f32 -> bf16, row-major.
// ---------------------------------------------------------------------------
__global__ __launch_bounds__(256) void cvt_wts(const float* __restrict__ Ww,
                                               const float* __restrict__ Zw,
                                               __hip_bfloat16* __restrict__ WwB,
                                               __hip_bfloat16* __restrict__ ZwB) {
    const int nW = TCH * CIN / 4;   // 49152 float4 chunks
    const int nZ = CIN * CH / 4;    // 16384
    int i = blockIdx.x * 256 + threadIdx.x;
    if (i < nW) {
        float4 v = ((const float4*)Ww)[i];
        bf16x4 o; o[0] = f2bf(v.x); o[1] = f2bf(v.y); o[2] = f2bf(v.z); o[3] = f2bf(v.w);
        ((bf16x4*)WwB)[i] = o;
    } else if (i < nW + nZ) {
        int j = i - nW;
        float4 v = ((const float4*)Zw)[j];
        bf16x4 o; o[0] = f2bf(v.x); o[1] = f2bf(v.y); o[2] = f2bf(v.z); o[3] = f2bf(v.w);
        ((bf16x4*)ZwB)[j] = o;
    }
}

// ---------------------------------------------------------------------------
// Kernel 0b: xT[n][q][c] bf16 = transpose+cvt of x[n][c][q] f32.
// ---------------------------------------------------------------------------
__global__ __launch_bounds__(256) void xpose_kernel(const float* __restrict__ x,
                                                    __hip_bfloat16* __restrict__ xT) {
    const int n = blockIdx.z, c0 = blockIdx.y * 64, q0 = blockIdx.x * 64;
    const int tid = threadIdx.x;
    const int mr = tid >> 4, mq = tid & 15;

    __shared__ char T[64 * 128];   // [q][64 c] bf16, byte ^= ((q&15)<<3)

    const float* xp = x + ((size_t)(n * CIN + c0 + mr * 4)) * HW + q0 + mq * 4;
    float4 r0 = *(const float4*)(xp);
    float4 r1 = *(const float4*)(xp + HW);
    float4 r2 = *(const float4*)(xp + 2 * HW);
    float4 r3 = *(const float4*)(xp + 3 * HW);
    const float* f0 = (const float*)&r0; const float* f1 = (const float*)&r1;
    const float* f2 = (const float*)&r2; const float* f3 = (const float*)&r3;
#pragma unroll
    for (int j = 0; j < 4; ++j) {
        int q = mq * 4 + j;
        bf16x4 v; v[0] = f2bf(f0[j]); v[1] = f2bf(f1[j]);
                  v[2] = f2bf(f2[j]); v[3] = f2bf(f3[j]);
        *(bf16x4*)(T + q * 128 + ((mr * 8) ^ ((q & 15) << 3))) = v;
    }
    __syncthreads();

    __hip_bfloat16* og = xT + ((size_t)n * HW + q0) * CIN + c0;
#pragma unroll
    for (int it = 0; it < 2; ++it) {
        int ch = it * 256 + tid, rr = ch >> 3, o8 = ch & 7;
        int sw = (rr & 15) << 3;
        bf16x4 lo = *(const bf16x4*)(T + rr * 128 + ((o8 * 16) ^ sw));
        bf16x4 hi = *(const bf16x4*)(T + rr * 128 + ((o8 * 16 + 8) ^ sw));
        bf16x8 v; v[0] = lo[0]; v[1] = lo[1]; v[2] = lo[2]; v[3] = lo[3];
                  v[4] = hi[0]; v[5] = hi[1]; v[6] = hi[2]; v[7] = hi[3];
        *(bf16x8*)(og + (size_t)rr * CIN + o8 * 8) = v;
    }
}

// ---------------------------------------------------------------------------
// Kernel 1: proj via MFMA (unchanged from R3).
// ---------------------------------------------------------------------------
__global__ __launch_bounds__(256) void proj_kernel(const __hip_bfloat16* __restrict__ xT,
                                                   const __hip_bfloat16* __restrict__ WwB,
                                                   const float* __restrict__ Wb,
                                                   __hip_bfloat16* __restrict__ Qt,
                                                   __hip_bfloat16* __restrict__ Kt,
                                                   __hip_bfloat16* __restrict__ Vg) {
    const int n  = blockIdx.z;
    const int m0 = blockIdx.y * 64;   // over 384
    const int q0 = blockIdx.x * 64;   // over 3136
    const int tid = threadIdx.x;
    const int lane = tid & 63, wv = tid >> 6;
    const int lr = lane & 15, hi = lane >> 4;

    __shared__ char Aw[64 * 128];  // [m][64 c] bf16, byte ^= ((r&7)<<4)
    __shared__ char Bx[64 * 128];  // [q][64 c]
    __shared__ char Ts[64 * 128];  // epilogue staging

    f32x4 acc[4] = {};
    const __hip_bfloat16* xn = xT + ((size_t)n * HW + q0) * CIN;

    for (int k0 = 0; k0 < CIN; k0 += 64) {
#pragma unroll
        for (int it = 0; it < 2; ++it) {
            int ch = it * 256 + tid, r = ch >> 3, o = ch & 7;
            int sw = (o * 16) ^ ((r & 7) << 4);
            bf16x8 a = *(const bf16x8*)(WwB + (size_t)(m0 + r) * CIN + k0 + o * 8);
            *(bf16x8*)(Aw + r * 128 + sw) = a;
            bf16x8 b = *(const bf16x8*)(xn + (size_t)r * CIN + k0 + o * 8);
            *(bf16x8*)(Bx + r * 128 + sw) = b;
        }
        __syncthreads();

        const int mrow = wv * 16 + lr;
#pragma unroll
        for (int ks = 0; ks < 2; ++ks) {
            bf16x8 af = *(const bf16x8*)(Aw + mrow * 128 +
                                         ((ks * 64 + hi * 16) ^ ((mrow & 7) << 4)));
#pragma unroll
            for (int kn = 0; kn < 4; ++kn) {
                int qrow = kn * 16 + lr;
                bf16x8 bfr = *(const bf16x8*)(Bx + qrow * 128 +
                                              ((ks * 64 + hi * 16) ^ ((qrow & 7) << 4)));
                acc[kn] = MFMA16(af, bfr, acc[kn]);
            }
        }
        __syncthreads();
    }

    const int region = m0 >> 7;     // 0=Q, 1=K, 2=V
    const int c0     = m0 & 127;    // 0 or 64

    float bias[4];
#pragma unroll
    for (int reg = 0; reg < 4; ++reg) bias[reg] = Wb[m0 + wv * 16 + hi * 4 + reg];

#pragma unroll
    for (int kn = 0; kn < 4; ++kn)
#pragma unroll
        for (int reg = 0; reg < 4; ++reg) {
            __hip_bfloat16 v = __float2bfloat16(acc[kn][reg] + bias[reg]);
            int row, colb;
            if (region < 2) { row = kn * 16 + lr; colb = (wv * 16 + hi * 4 + reg) * 2; }
            else            { row = wv * 16 + hi * 4 + reg; colb = (kn * 16 + lr) * 2; }
            *(__hip_bfloat16*)(Ts + row * 128 + (colb ^ ((row & 7) << 4))) = v;
        }
    __syncthreads();

    __hip_bfloat16* base;
    size_t rstride;
    if (region == 0)      { base = Qt + (size_t)n * HW * CH + (size_t)q0 * CH + c0; rstride = CH; }
    else if (region == 1) { base = Kt + (size_t)n * HW * CH + (size_t)q0 * CH + c0; rstride = CH; }
    else                  { base = Vg + (size_t)n * CH * HW + (size_t)c0 * HW + q0; rstride = HW; }

#pragma unroll
    for (int it = 0; it < 2; ++it) {
        int ch = it * 256 + tid, rr = ch >> 3, o = ch & 7;
        bf16x8 v = *(const bf16x8*)(Ts + rr * 128 + ((o * 16) ^ ((rr & 7) << 4)));
        *(bf16x8*)(base + (size_t)rr * rstride + o * 8) = v;
    }
}

// ---------------------------------------------------------------------------
// Kernel 2: flash attention, swapped-QK^T + in-register P + async staging.
//   S^T = mfma(K, Q)  -> lane holds S[q=lr][k=kt*16+hi*4+reg]
//   O^T = mfma(V^T, P^T) -> O^T[c=cn*16+hi*4+reg][q=lr]
// ---------------------------------------------------------------------------
__global__ __launch_bounds__(256, 2) void attn_kernel(
        const __hip_bfloat16* __restrict__ Qt,   // [NB][HW][CH]
        const __hip_bfloat16* __restrict__ Kt,   // [NB][HW][CH]
        const __hip_bfloat16* __restrict__ Vg,   // [NB][CH][HW]
        __hip_bfloat16* __restrict__ att) {      // [NB][HW][CH]
    const int n  = blockIdx.y;
    const int q0 = blockIdx.x * 64;
    const int tid  = threadIdx.x;
    const int lane = tid & 63, wv = tid >> 6;
    const int lr = lane & 15, hi = lane >> 4;
    const int b = hi & 1, g = hi >> 1;

    __shared__ char smem[32768];
    char* Ks = smem;            // 64 rows * 256B (k-major, c contiguous), swizzled
    char* Vt = smem + 16384;    // 128 rows * 128B (c-major, v contiguous), swizzled

    const __hip_bfloat16* Qg = Qt + ((size_t)n * HW + q0) * CH;
    const __hip_bfloat16* Kg = Kt + (size_t)n * HW * CH;
    const __hip_bfloat16* Vp = Vg + (size_t)n * CH * HW;

    // per-thread staging geometry (K: 4 chunks of 16B; V: 4 chunks of 16B)
    const int krow_s = tid >> 4, kcol_s = tid & 15;
    const int vrow_s = tid >> 3, vcol_s = tid & 7;
    const int kswz = (kcol_s * 16) ^ ((krow_s & 7) << 4);
    const int vswz = (vcol_s * 16) ^ ((vrow_s & 7) << 4);

    bf16x8 kreg[4], vreg[4];
    // issue tile-0 loads immediately (latency hides under Q staging)
#pragma unroll
    for (int it = 0; it < 4; ++it)
        kreg[it] = *(const bf16x8*)(Kg + (size_t)(it * 16 + krow_s) * CH + kcol_s * 8);
#pragma unroll
    for (int it = 0; it < 4; ++it)
        vreg[it] = *(const bf16x8*)(Vp + (size_t)(it * 32 + vrow_s) * HW + vcol_s * 8);

    // stage Q through Ks region, pull B-frags (q rows) to registers
#pragma unroll
    for (int it = 0; it < 4; ++it) {
        bf16x8 v = *(const bf16x8*)(Qg + (size_t)(it * 16 + krow_s) * CH + kcol_s * 8);
        *(bf16x8*)(Ks + (it * 16 + krow_s) * 256 + kswz) = v;
    }
    __syncthreads();
    const int qrow = wv * 16 + lr;
    bf16x8 qf[4];
#pragma unroll
    for (int cs = 0; cs < 4; ++cs)
        qf[cs] = *(const bf16x8*)(Ks + qrow * 256 + ((cs * 64 + hi * 16) ^ ((qrow & 7) << 4)));
    __syncthreads();

    // write tile 0 into LDS
#pragma unroll
    for (int it = 0; it < 4; ++it)
        *(bf16x8*)(Ks + (it * 16 + krow_s) * 256 + kswz) = kreg[it];
#pragma unroll
    for (int it = 0; it < 4; ++it)
        *(bf16x8*)(Vt + (it * 32 + vrow_s) * 128 + vswz) = vreg[it];
    __syncthreads();

    f32x4 O[8] = {};                  // O^T: rows c=cn*16+hi*4+reg, col q=lr
    float m_i = -1e30f, l_i = 0.f;    // per-lane state for q = lr

    const int NT = HW / 64;           // 49
    for (int t = 0; t < NT; ++t) {
        // prefetch next tile into registers
        if (t + 1 < NT) {
            const int k0n = (t + 1) * 64;
#pragma unroll
            for (int it = 0; it < 4; ++it)
                kreg[it] = *(const bf16x8*)(Kg + (size_t)(k0n + it * 16 + krow_s) * CH + kcol_s * 8);
#pragma unroll
            for (int it = 0; it < 4; ++it)
                vreg[it] = *(const bf16x8*)(Vp + (size_t)(it * 32 + vrow_s) * HW + k0n + vcol_s * 8);
        }

        // S^T = K Q^T : sacc[kt] rows k=kt*16.., cols q (wave's 16 q)
        f32x4 sacc[4] = {};
#pragma unroll
        for (int kt = 0; kt < 4; ++kt) {
            int krow = kt * 16 + lr;
#pragma unroll
            for (int cs = 0; cs < 4; ++cs) {
                bf16x8 kf = *(const bf16x8*)(Ks + krow * 256 +
                                             ((cs * 64 + hi * 16) ^ ((lr & 7) << 4)));
                sacc[kt] = MFMA16(kf, qf[cs], sacc[kt]);
            }
        }

        // online softmax, all in-lane (q = lr), cross-hi via 2 shuffles
        float pmax = sacc[0][0];
#pragma unroll
        for (int kt = 0; kt < 4; ++kt)
#pragma unroll
            for (int reg = 0; reg < 4; ++reg) pmax = fmaxf(pmax, sacc[kt][reg]);
        pmax = fmaxf(pmax, __shfl_xor(pmax, 16));
        pmax = fmaxf(pmax, __shfl_xor(pmax, 32));

        if (__any(pmax > m_i)) {
            float nm = fmaxf(m_i, pmax);
            float f  = __expf((m_i - nm) * SCALE);
            l_i *= f; m_i = nm;
#pragma unroll
            for (int cn = 0; cn < 8; ++cn) O[cn] *= f;
        }

        float pp[4][4];
        float rs = 0.f;
#pragma unroll
        for (int kt = 0; kt < 4; ++kt)
#pragma unroll
            for (int reg = 0; reg < 4; ++reg) {
                pp[kt][reg] = __expf((sacc[kt][reg] - m_i) * SCALE);
                rs += pp[kt][reg];
            }
        rs += __shfl_xor(rs, 16);
        rs += __shfl_xor(rs, 32);
        l_i += rs;

        // pack P to bf16 pairs: pk[kt][h] covers k = kt*16+hi*4+{2h,2h+1}
        unsigned pk[4][2];
#pragma unroll
        for (int kt = 0; kt < 4; ++kt) {
            pk[kt][0] = pack2bf(pp[kt][0], pp[kt][1]);
            pk[kt][1] = pack2bf(pp[kt][2], pp[kt][3]);
        }

        // O^T += V^T P^T ; P-frags assembled in-register via 8 shuffles
#pragma unroll
        for (int ks = 0; ks < 2; ++ks) {
            union { unsigned u[4]; bf16x8 v; } pf;
#pragma unroll
            for (int h = 0; h < 2; ++h) {
                unsigned send1 = b ? pk[2 * ks + 1][h] : pk[2 * ks][h];
                unsigned send2 = b ? pk[2 * ks][h]     : pk[2 * ks + 1][h];
                unsigned r1 = __shfl((int)send1, (2 * b + g) * 16 + lr);
                unsigned r2 = __shfl((int)send2, (2 * b + (g ^ 1)) * 16 + lr);
                pf.u[h]     = g ? r2 : r1;
                pf.u[h + 2] = g ? r1 : r2;
            }
#pragma unroll
            for (int cn = 0; cn < 8; ++cn) {
                int vr = cn * 16 + lr;
                bf16x8 vb = *(const bf16x8*)(Vt + vr * 128 +
                                             ((ks * 64 + hi * 16) ^ ((lr & 7) << 4)));
                O[cn] = MFMA16(vb, pf.v, O[cn]);
            }
        }

        __syncthreads();              // all waves done reading Ks/Vt
        if (t + 1 < NT) {
#pragma unroll
            for (int it = 0; it < 4; ++it)
                *(bf16x8*)(Ks + (it * 16 + krow_s) * 256 + kswz) = kreg[it];
#pragma unroll
            for (int it = 0; it < 4; ++it)
                *(bf16x8*)(Vt + (it * 32 + vrow_s) * 128 + vswz) = vreg[it];
        }
        __syncthreads();
    }

    // normalize and stage O^T -> att[q][c] bf16 through LDS (Ks region)
    float inv = 1.f / l_i;
    const int qrow_e = wv * 16 + lr;
#pragma unroll
    for (int cn = 0; cn < 8; ++cn) {
        unsigned u0 = pack2bf(O[cn][0] * inv, O[cn][1] * inv);
        unsigned u1 = pack2bf(O[cn][2] * inv, O[cn][3] * inv);
        int colb = cn * 32 + hi * 8;
        *(unsigned*)(Ks + qrow_e * 256 + ((colb)     ^ ((lr & 7) << 4))) = u0;
        *(unsigned*)(Ks + qrow_e * 256 + ((colb + 4) ^ ((lr & 7) << 4))) = u1;
    }
    __syncthreads();
    __hip_bfloat16* ag = att + ((size_t)n * HW + q0) * CH;
#pragma unroll
    for (int it = 0; it < 4; ++it) {
        int ch = it * 256 + tid, r = ch >> 4, o = ch & 15;
        bf16x8 v = *(const bf16x8*)(Ks + r * 256 + ((o * 16) ^ ((r & 7) << 4)));
        *(bf16x8*)(ag + (size_t)r * CH + o * 8) = v;
    }
}

// ---------------------------------------------------------------------------
// Kernel 3: z = ZwB @ att[n] via MFMA (K=128), BN + residual. Unchanged.
// ---------------------------------------------------------------------------
__global__ __launch_bounds__(256) void zbn_kernel(const __hip_bfloat16* __restrict__ att,
                                                  const __hip_bfloat16* __restrict__ ZwB,
                                                  const float* __restrict__ gamma,
                                                  const float* __restrict__ beta,
                                                  const float* __restrict__ mean,
                                                  const float* __restrict__ var,
                                                  const float* __restrict__ x,
                                                  float* __restrict__ out) {
    const int n  = blockIdx.z;
    const int m0 = blockIdx.y * 64;   // over 512
    const int q0 = blockIdx.x * 64;   // over 3136
    const int tid = threadIdx.x;
    const int lane = tid & 63, wv = tid >> 6;
    const int lr = lane & 15, hi = lane >> 4;

    __shared__ char smem[32768];
    char* Az = smem;            // [m][128 c] bf16, 64 rows * 256B, swizzled
    char* Ba = smem + 16384;    // [q][128 c] bf16

#pragma unroll
    for (int it = 0; it < 4; ++it) {
        int ch = it * 256 + tid, r = ch >> 4, o = ch & 15;
        int sw = (o * 16) ^ ((r & 7) << 4);
        bf16x8 a = *(const bf16x8*)(ZwB + (size_t)(m0 + r) * CH + o * 8);
        *(bf16x8*)(Az + r * 256 + sw) = a;
        bf16x8 b = *(const bf16x8*)(att + ((size_t)n * HW + q0 + r) * CH + o * 8);
        *(bf16x8*)(Ba + r * 256 + sw) = b;
    }
    __syncthreads();

    f32x4 acc[4] = {};
    const int mrow = wv * 16 + lr;
#pragma unroll
    for (int ks = 0; ks < 4; ++ks) {
        bf16x8 af = *(const bf16x8*)(Az + mrow * 256 +
                                     ((ks * 64 + hi * 16) ^ ((mrow & 7) << 4)));
#pragma unroll
        for (int kn = 0; kn < 4; ++kn) {
            int qrow = kn * 16 + lr;
            bf16x8 bfr = *(const bf16x8*)(Ba + qrow * 256 +
                                          ((ks * 64 + hi * 16) ^ ((qrow & 7) << 4)));
            acc[kn] = MFMA16(af, bfr, acc[kn]);
        }
    }
    __syncthreads();   // smem reused for epilogue staging

    float inv[4], add[4];
#pragma unroll
    for (int reg = 0; reg < 4; ++reg) {
        int m = m0 + wv * 16 + hi * 4 + reg;
        inv[reg] = gamma[m] * rsqrtf(var[m] + BNEPS);
        add[reg] = beta[m] - mean[m] * inv[reg];
    }

#pragma unroll
    for (int kn = 0; kn < 4; ++kn)
#pragma unroll
        for (int reg = 0; reg < 4; ++reg) {
            int row = wv * 16 + hi * 4 + reg;
            int colb = (kn * 16 + lr) * 4;
            *(float*)(smem + row * 256 + (colb ^ ((row & 7) << 4))) =
                acc[kn][reg] * inv[reg] + add[reg];
        }
    __syncthreads();

#pragma unroll
    for (int it = 0; it < 4; ++it) {
        int ch = it * 256 + tid, rr = ch >> 4, o = ch & 15;
        f32x4 v = *(const f32x4*)(smem + rr * 256 + ((o * 16) ^ ((rr & 7) << 4)));
        size_t idx = (size_t)n * CIN * HW + (size_t)(m0 + rr) * HW + q0 + o * 4;
        float4 xv = *(const float4*)(x + idx);
        float4 ov; ov.x = v[0] + xv.x; ov.y = v[1] + xv.y;
                   ov.z = v[2] + xv.z; ov.w = v[3] + xv.w;
        *(float4*)(out + idx) = ov;
    }
}

// ---------------------------------------------------------------------------
extern "C" void kernel_launch(void* const* d_in, const int* in_sizes, int n_in,
                              void* d_out, int out_size, void* d_ws, size_t ws_size,
                              hipStream_t stream) {
    const float* x     = (const float*)d_in[0];
    const float* Ww    = (const float*)d_in[1];
    const float* Wb    = (const float*)d_in[2];
    const float* Zw    = (const float*)d_in[3];
    const float* gamma = (const float*)d_in[4];
    const float* beta  = (const float*)d_in[5];
    const float* mean  = (const float*)d_in[6];
    const float* var   = (const float*)d_in[7];
    float* out = (float*)d_out;

    const size_t xT_bytes  = (size_t)NB * HW * CIN * 2;   // 25,690,112
    const size_t qkv_bytes = (size_t)NB * HW * CH * 2;    //  6,422,528 each
    const size_t att_bytes = qkv_bytes;
    const size_t WwB_bytes = (size_t)TCH * CIN * 2;       //    393,216
    const size_t ZwB_bytes = (size_t)CIN * CH * 2;        //    131,072
    const size_t total = xT_bytes + 3 * qkv_bytes + att_bytes + WwB_bytes + ZwB_bytes;

    __hip_bfloat16 *xT, *Qt, *Kt, *Vgb, *attb, *WwB, *ZwB;
    if (ws_size >= total) {
        char* w = (char*)d_ws;
        xT   = (__hip_bfloat16*)w;                          w += xT_bytes;
        Qt   = (__hip_bfloat16*)w;                          w += qkv_bytes;
        Kt   = (__hip_bfloat16*)w;                          w += qkv_bytes;
        Vgb  = (__hip_bfloat16*)w;                          w += qkv_bytes;
        attb = (__hip_bfloat16*)w;                          w += att_bytes;
        WwB  = (__hip_bfloat16*)w;                          w += WwB_bytes;
        ZwB  = (__hip_bfloat16*)w;
    } else {
        char* w = (char*)d_out;
        xT   = (__hip_bfloat16*)w;                          w += xT_bytes;
        Qt   = (__hip_bfloat16*)w;                          w += qkv_bytes;
        Kt   = (__hip_bfloat16*)w;                          w += qkv_bytes;
        Vgb  = (__hip_bfloat16*)w;
        char* v = (char*)d_ws;
        attb = (__hip_bfloat16*)v;                          v += att_bytes;
        WwB  = (__hip_bfloat16*)v;                          v += WwB_bytes;
        ZwB  = (__hip_bfloat16*)v;
    }

    cvt_wts<<<dim3(256), 256, 0, stream>>>(Ww, Zw, WwB, ZwB);
    xpose_kernel<<<dim3(HW / 64, CIN / 64, NB), 256, 0, stream>>>(x, xT);
    proj_kernel<<<dim3(HW / 64, TCH / 64, NB), 256, 0, stream>>>(xT, WwB, Wb, Qt, Kt, Vgb);
    attn_kernel<<<dim3(HW / 64, NB), 256, 0, stream>>>(Qt, Kt, Vgb, attb);
    zbn_kernel<<<dim3(HW / 64, CIN / 64, NB), 256, 0, stream>>>(attb, ZwB, gamma, beta,
                                                                mean, var, x, out);
}